// Round 10
// baseline (154.418 us; speedup 1.0000x reference)
//
#include <hip/hip_runtime.h>
#include <stdint.h>

// FilteredLReLU: up2(17-tap) -> *2 -> lrelu(0.01) -> down2(17-tap), fused.
// Persistent-row + software-pipelined f16-dot2 version.
//   - 1 block per row; each thread handles 8 tiles of 16 outputs.
//   - ping-pong register buffers: next tile's 8 float4 loads issued
//     before computing the current tile (latency hidden by ILP).
//   - tap preamble amortized once per block.
//   - row-edge tiles (2/row) handled by a tiny scalar-f32 side kernel.
//
//   ge[m] = lrelu( sum fe[j]*x[m-4+j] ), go[m] = lrelu( sum fo[j]*x[m-3+j] )
//   z[t]  = sum de[j]*ge[t-4+j] + sum dd[j]*go[t-4+j]   (UP gain in fe/fo)

#define T_LEN 32768
#define R_OUT 16
#define TROW  (T_LEN / R_OUT)    // 2048 tiles per row
#define ITERS (TROW / 256)       // 8 tiles per thread

typedef __fp16 h16x2 __attribute__((ext_vector_type(2)));

__device__ __forceinline__ uint32_t pkrtz(float lo, float hi) {
    h16x2 p = __builtin_amdgcn_cvt_pkrtz(lo, hi);
    return __builtin_bit_cast(uint32_t, p);
}
__device__ __forceinline__ float fdot2(uint32_t a, uint32_t b, float c) {
    return __builtin_amdgcn_fdot2(__builtin_bit_cast(h16x2, a),
                                  __builtin_bit_cast(h16x2, b), c, false);
}
__device__ __forceinline__ float lrelu(float v) { return fmaxf(v, 0.01f * v); }
__device__ __forceinline__ uint32_t rfl(uint32_t v) {
    return __builtin_amdgcn_readfirstlane(v);
}

struct Taps { uint32_t fep[5], fop[4], dp[9]; };

__device__ __forceinline__ void compute_tile_fast(
    const float4* b, float* __restrict__ orow, int t, const Taps& tp)
{
    float xv[32];
    #pragma unroll
    for (int k = 0; k < 8; ++k) {
        xv[4 * k + 0] = b[k].x; xv[4 * k + 1] = b[k].y;
        xv[4 * k + 2] = b[k].z; xv[4 * k + 3] = b[k].w;
    }
    uint32_t xa[16], xs[16];
    #pragma unroll
    for (int k = 0; k < 16; ++k) xa[k] = pkrtz(xv[2 * k], xv[2 * k + 1]);
    #pragma unroll
    for (int k = 0; k < 15; ++k)
        xs[k] = (xa[k] >> 16) | (xa[k + 1] << 16);
    xs[15] = xa[15] >> 16;

    float acc[R_OUT];
    #pragma unroll
    for (int ml = 0; ml < R_OUT + 8; ++ml) {
        const int e = ml / 2;
        float ae;
        if ((ml & 1) == 0) {
            ae = fdot2(tp.fep[0], xa[e], 0.0f);
            ae = fdot2(tp.fep[1], xa[e + 1], ae);
            ae = fdot2(tp.fep[2], xa[e + 2], ae);
            ae = fdot2(tp.fep[3], xa[e + 3], ae);
            ae = fdot2(tp.fep[4], xa[e + 4], ae);
        } else {
            ae = fdot2(tp.fep[0], xs[e], 0.0f);
            ae = fdot2(tp.fep[1], xs[e + 1], ae);
            ae = fdot2(tp.fep[2], xs[e + 2], ae);
            ae = fdot2(tp.fep[3], xs[e + 3], ae);
            ae = fdot2(tp.fep[4], xs[e + 4], ae);
        }
        float g = lrelu(ae);

        float h = 0.0f;
        if (ml < R_OUT + 7) {
            float ao;
            if ((ml & 1) == 0) {
                ao = fdot2(tp.fop[0], xs[e], 0.0f);
                ao = fdot2(tp.fop[1], xs[e + 1], ao);
                ao = fdot2(tp.fop[2], xs[e + 2], ao);
                ao = fdot2(tp.fop[3], xs[e + 3], ao);
            } else {
                ao = fdot2(tp.fop[0], xa[e + 1], 0.0f);
                ao = fdot2(tp.fop[1], xa[e + 2], ao);
                ao = fdot2(tp.fop[2], xa[e + 3], ao);
                ao = fdot2(tp.fop[3], xa[e + 4], ao);
            }
            h = lrelu(ao);
        }

        const uint32_t p = pkrtz(g, h);
        #pragma unroll
        for (int r = 0; r < R_OUT; ++r) {
            if (r >= ml - 8 && r <= ml) {
                if (r == ml) acc[r] = fdot2(tp.dp[0], p, 0.0f);
                else         acc[r] = fdot2(tp.dp[ml - r], p, acc[r]);
            }
        }
    }

    float4* op = reinterpret_cast<float4*>(orow + t);
    #pragma unroll
    for (int k = 0; k < R_OUT / 4; ++k)
        op[k] = make_float4(acc[4 * k + 0], acc[4 * k + 1],
                            acc[4 * k + 2], acc[4 * k + 3]);
}

__global__ __launch_bounds__(256, 4) void flrelu_pipe(
    const float* __restrict__ x,
    const float* __restrict__ up,
    const float* __restrict__ dn,
    float* __restrict__ out)
{
    const int tid = threadIdx.x;
    const int row = blockIdx.x;
    const float* __restrict__ xrow = x + (size_t)row * T_LEN;
    float* __restrict__ orow       = out + (size_t)row * T_LEN;

    Taps tp;
    {
        float fe[9], fo[8], de[9], dd[8];
        #pragma unroll
        for (int j = 0; j < 9; ++j) { fe[j] = 2.0f * up[2 * j]; de[j] = dn[2 * j]; }
        #pragma unroll
        for (int j = 0; j < 8; ++j) { fo[j] = 2.0f * up[2 * j + 1]; dd[j] = dn[2 * j + 1]; }
        #pragma unroll
        for (int q = 0; q < 4; ++q) tp.fep[q] = rfl(pkrtz(fe[2 * q], fe[2 * q + 1]));
        tp.fep[4] = rfl(pkrtz(fe[8], 0.0f));
        #pragma unroll
        for (int q = 0; q < 4; ++q) tp.fop[q] = rfl(pkrtz(fo[2 * q], fo[2 * q + 1]));
        #pragma unroll
        for (int j = 0; j < 8; ++j) tp.dp[j] = rfl(pkrtz(de[j], dd[j]));
        tp.dp[8] = rfl(pkrtz(de[8], 0.0f));
    }

    float4 bufA[8], bufB[8];

    // prologue: load slot tid (iter 0); tile 0 is edge-kernel territory
    if (tid != 0) {
        const float4* xp = reinterpret_cast<const float4*>(xrow + tid * 16 - 8);
        #pragma unroll
        for (int k = 0; k < 8; ++k) bufA[k] = xp[k];
    }

    #pragma unroll 1
    for (int it = 0; it < ITERS; it += 2) {
        const int idxA = it * 256 + tid;
        const int idxB = idxA + 256;
        const bool vA = (idxA != 0) && (idxA != TROW - 1);
        const bool vB = (idxB != TROW - 1);

        if (vB) {   // prefetch B while A computes
            const float4* xp =
                reinterpret_cast<const float4*>(xrow + idxB * 16 - 8);
            #pragma unroll
            for (int k = 0; k < 8; ++k) bufB[k] = xp[k];
        }
        if (vA) compute_tile_fast(bufA, orow, idxA * 16, tp);

        if (it + 2 < ITERS) {   // prefetch next A while B computes
            const int idxA2 = idxA + 512;
            const float4* xp =
                reinterpret_cast<const float4*>(xrow + idxA2 * 16 - 8);
            #pragma unroll
            for (int k = 0; k < 8; ++k) bufA[k] = xp[k];
        }
        if (vB) compute_tile_fast(bufB, orow, idxB * 16, tp);
    }
}

// Edge tiles (first/last 16 outputs of each row): scalar f32, guarded.
__global__ __launch_bounds__(256) void flrelu_edge(
    const float* __restrict__ x,
    const float* __restrict__ up,
    const float* __restrict__ dn,
    float* __restrict__ out, int nedge)
{
    const int id = blockIdx.x * 256 + threadIdx.x;
    if (id >= nedge) return;
    const int row = id >> 1;
    const int t   = (id & 1) ? (T_LEN - R_OUT) : 0;
    const float* __restrict__ xrow = x + (size_t)row * T_LEN;
    float* __restrict__ orow       = out + (size_t)row * T_LEN;

    float fe[9], fo[8], de[9], dd[8];
    #pragma unroll
    for (int j = 0; j < 9; ++j) { fe[j] = 2.0f * up[2 * j]; de[j] = dn[2 * j]; }
    #pragma unroll
    for (int j = 0; j < 8; ++j) { fo[j] = 2.0f * up[2 * j + 1]; dd[j] = dn[2 * j + 1]; }

    float xv[R_OUT + 16];
    #pragma unroll
    for (int i = 0; i < R_OUT + 16; ++i) {
        int g = t - 8 + i;
        xv[i] = (g >= 0 && g < T_LEN) ? xrow[g] : 0.0f;
    }
    float acc[R_OUT];
    #pragma unroll
    for (int r = 0; r < R_OUT; ++r) acc[r] = 0.0f;

    #pragma unroll
    for (int ml = 0; ml < R_OUT + 8; ++ml) {
        float ae = 0.0f;
        #pragma unroll
        for (int j = 0; j < 9; ++j) ae = fmaf(fe[j], xv[ml + j], ae);
        float g = lrelu(ae);
        int m = t - 4 + ml;
        if (m < 0 || m >= T_LEN) g = 0.0f;   // dn conv zero-pads y
        #pragma unroll
        for (int r = 0; r < R_OUT; ++r)
            if (r >= ml - 8 && r <= ml)
                acc[r] = fmaf(de[ml - r], g, acc[r]);

        if (ml < R_OUT + 7) {
            float ao = 0.0f;
            #pragma unroll
            for (int j = 0; j < 8; ++j) ao = fmaf(fo[j], xv[ml + 1 + j], ao);
            float h = lrelu(ao);
            if (m < 0 || m >= T_LEN) h = 0.0f;
            #pragma unroll
            for (int r = 0; r < R_OUT; ++r)
                if (r >= ml - 7 && r <= ml)
                    acc[r] = fmaf(dd[ml - r], h, acc[r]);
        }
    }

    float4* op = reinterpret_cast<float4*>(orow + t);
    #pragma unroll
    for (int k = 0; k < R_OUT / 4; ++k)
        op[k] = make_float4(acc[4 * k + 0], acc[4 * k + 1],
                            acc[4 * k + 2], acc[4 * k + 3]);
}

extern "C" void kernel_launch(void* const* d_in, const int* in_sizes, int n_in,
                              void* d_out, int out_size, void* d_ws, size_t ws_size,
                              hipStream_t stream) {
    const float* x  = (const float*)d_in[0];
    const float* up = (const float*)d_in[1];
    const float* dn = (const float*)d_in[2];
    float* out      = (float*)d_out;

    const int rows = in_sizes[0] / T_LEN;            // 2048
    flrelu_pipe<<<rows, 256, 0, stream>>>(x, up, dn, out);
    const int nedge = rows * 2;
    flrelu_edge<<<(nedge + 255) / 256, 256, 0, stream>>>(x, up, dn, out, nedge);
}

// Round 11
// 137.848 us; speedup vs baseline: 1.1202x; 1.1202x over previous
//
#include <hip/hip_runtime.h>
#include <stdint.h>

// FilteredLReLU: up2(17-tap) -> *2 -> lrelu(0.01) -> down2(17-tap), fused.
// f16 dot2 streaming (R9 structure) + anti-rematerialization barriers:
// zero-cost asm register ties on the packed xa/xs values force them to
// stay resident in VGPRs instead of being recomputed at each use
// (R9: VGPR=36 < live set ~55 -> compiler remat'd packs, ~2x VALU ops).
//
//   ge[m] = lrelu( sum fe[j]*x[m-4+j] ), go[m] = lrelu( sum fo[j]*x[m-3+j] )
//   z[t]  = sum de[j]*ge[t-4+j] + sum dd[j]*go[t-4+j]   (UP gain in fe/fo)

#define T_LEN 32768
#define R_OUT 16
#define TPR   (T_LEN / R_OUT)   // 2048 threads per row

typedef __fp16 h16x2 __attribute__((ext_vector_type(2)));

__device__ __forceinline__ uint32_t pkrtz(float lo, float hi) {
    h16x2 p = __builtin_amdgcn_cvt_pkrtz(lo, hi);
    return __builtin_bit_cast(uint32_t, p);
}
__device__ __forceinline__ float fdot2(uint32_t a, uint32_t b, float c) {
    return __builtin_amdgcn_fdot2(__builtin_bit_cast(h16x2, a),
                                  __builtin_bit_cast(h16x2, b), c, false);
}
__device__ __forceinline__ float lrelu(float v) { return fmaxf(v, 0.01f * v); }
__device__ __forceinline__ uint32_t rfl(uint32_t v) {
    return __builtin_amdgcn_readfirstlane(v);
}
// Opaque register tie: value must materialize in a VGPR; producers can't
// be rematerialized past this point. Generates zero instructions.
__device__ __forceinline__ void pin(uint32_t& v) {
    asm volatile("" : "+v"(v));
}

__global__ __launch_bounds__(256, 2) void flrelu_dot2p(
    const float* __restrict__ x,
    const float* __restrict__ up,
    const float* __restrict__ dn,
    float* __restrict__ out)
{
    const int gid = blockIdx.x * 256 + threadIdx.x;
    const int row = gid >> 11;                 // / TPR
    const int t   = (gid & (TPR - 1)) * R_OUT;
    const float* __restrict__ xrow = x + (size_t)row * T_LEN;
    float* __restrict__ orow       = out + (size_t)row * T_LEN;

    // f32 taps (uniform). UP gain folded into fe/fo.
    float fe[9], fo[8], de[9], dd[8];
    #pragma unroll
    for (int j = 0; j < 9; ++j) { fe[j] = 2.0f * up[2 * j]; de[j] = dn[2 * j]; }
    #pragma unroll
    for (int j = 0; j < 8; ++j) { fo[j] = 2.0f * up[2 * j + 1]; dd[j] = dn[2 * j + 1]; }

    if (t >= 8 && t + R_OUT + 8 <= T_LEN) {
        // ---------------- fast f16-dot2 path (interior) ----------------
        uint32_t fep[5], fop[4], dp[9];
        #pragma unroll
        for (int q = 0; q < 4; ++q) fep[q] = rfl(pkrtz(fe[2 * q], fe[2 * q + 1]));
        fep[4] = rfl(pkrtz(fe[8], 0.0f));
        #pragma unroll
        for (int q = 0; q < 4; ++q) fop[q] = rfl(pkrtz(fo[2 * q], fo[2 * q + 1]));
        #pragma unroll
        for (int j = 0; j < 8; ++j) dp[j] = rfl(pkrtz(de[j], dd[j]));
        dp[8] = rfl(pkrtz(de[8], 0.0f));

        // load x[t-8 .. t+23]
        float xv[32];
        const float4* xp = reinterpret_cast<const float4*>(xrow + t - 8);
        #pragma unroll
        for (int k = 0; k < 8; ++k) {
            float4 v = xp[k];
            xv[4 * k + 0] = v.x; xv[4 * k + 1] = v.y;
            xv[4 * k + 2] = v.z; xv[4 * k + 3] = v.w;
        }

        // f16 pairs: aligned + shifted-by-1; pinned so they stay resident
        uint32_t xa[16], xs[16];
        #pragma unroll
        for (int k = 0; k < 16; ++k) {
            xa[k] = pkrtz(xv[2 * k], xv[2 * k + 1]);
            pin(xa[k]);
        }
        #pragma unroll
        for (int k = 0; k < 15; ++k) {
            xs[k] = (xa[k] >> 16) | (xa[k + 1] << 16);   // v_alignbit_b32
            pin(xs[k]);
        }
        xs[15] = xa[15] >> 16;
        pin(xs[15]);

        float acc[R_OUT];

        #pragma unroll
        for (int ml = 0; ml < R_OUT + 8; ++ml) {
            const int e = ml / 2;
            float ae;
            if ((ml & 1) == 0) {
                ae = fdot2(fep[0], xa[e], 0.0f);
                ae = fdot2(fep[1], xa[e + 1], ae);
                ae = fdot2(fep[2], xa[e + 2], ae);
                ae = fdot2(fep[3], xa[e + 3], ae);
                ae = fdot2(fep[4], xa[e + 4], ae);
            } else {
                ae = fdot2(fep[0], xs[e], 0.0f);
                ae = fdot2(fep[1], xs[e + 1], ae);
                ae = fdot2(fep[2], xs[e + 2], ae);
                ae = fdot2(fep[3], xs[e + 3], ae);
                ae = fdot2(fep[4], xs[e + 4], ae);
            }
            float g = lrelu(ae);

            float h = 0.0f;
            if (ml < R_OUT + 7) {
                float ao;
                if ((ml & 1) == 0) {
                    ao = fdot2(fop[0], xs[e], 0.0f);
                    ao = fdot2(fop[1], xs[e + 1], ao);
                    ao = fdot2(fop[2], xs[e + 2], ao);
                    ao = fdot2(fop[3], xs[e + 3], ao);
                } else {
                    ao = fdot2(fop[0], xa[e + 1], 0.0f);
                    ao = fdot2(fop[1], xa[e + 2], ao);
                    ao = fdot2(fop[2], xa[e + 3], ao);
                    ao = fdot2(fop[3], xa[e + 4], ao);
                }
                h = lrelu(ao);
            }

            // scatter: acc[r] += de[ml-r]*g + dd[ml-r]*h  (dd[8] == 0 pad)
            uint32_t p = pkrtz(g, h);
            pin(p);
            #pragma unroll
            for (int r = 0; r < R_OUT; ++r) {
                if (r >= ml - 8 && r <= ml) {
                    if (r == ml) acc[r] = fdot2(dp[0], p, 0.0f);
                    else         acc[r] = fdot2(dp[ml - r], p, acc[r]);
                }
            }
        }

        float4* op = reinterpret_cast<float4*>(orow + t);
        #pragma unroll
        for (int k = 0; k < R_OUT / 4; ++k)
            op[k] = make_float4(acc[4 * k + 0], acc[4 * k + 1],
                                acc[4 * k + 2], acc[4 * k + 3]);
    } else {
        // ---------------- scalar f32 boundary path ----------------
        float xv[R_OUT + 16];
        #pragma unroll
        for (int i = 0; i < R_OUT + 16; ++i) {
            int g = t - 8 + i;
            xv[i] = (g >= 0 && g < T_LEN) ? xrow[g] : 0.0f;
        }
        float acc[R_OUT];
        #pragma unroll
        for (int r = 0; r < R_OUT; ++r) acc[r] = 0.0f;

        #pragma unroll
        for (int ml = 0; ml < R_OUT + 8; ++ml) {
            float ae = 0.0f;
            #pragma unroll
            for (int j = 0; j < 9; ++j) ae = fmaf(fe[j], xv[ml + j], ae);
            float g = lrelu(ae);
            int m = t - 4 + ml;
            if (m < 0 || m >= T_LEN) g = 0.0f;   // dn conv zero-pads y
            #pragma unroll
            for (int r = 0; r < R_OUT; ++r)
                if (r >= ml - 8 && r <= ml)
                    acc[r] = fmaf(de[ml - r], g, acc[r]);

            if (ml < R_OUT + 7) {
                float ao = 0.0f;
                #pragma unroll
                for (int j = 0; j < 8; ++j) ao = fmaf(fo[j], xv[ml + 1 + j], ao);
                float h = lrelu(ao);
                if (m < 0 || m >= T_LEN) h = 0.0f;
                #pragma unroll
                for (int r = 0; r < R_OUT; ++r)
                    if (r >= ml - 7 && r <= ml)
                        acc[r] = fmaf(dd[ml - r], h, acc[r]);
            }
        }

        float4* op = reinterpret_cast<float4*>(orow + t);
        #pragma unroll
        for (int k = 0; k < R_OUT / 4; ++k)
            op[k] = make_float4(acc[4 * k + 0], acc[4 * k + 1],
                                acc[4 * k + 2], acc[4 * k + 3]);
    }
}

extern "C" void kernel_launch(void* const* d_in, const int* in_sizes, int n_in,
                              void* d_out, int out_size, void* d_ws, size_t ws_size,
                              hipStream_t stream) {
    const float* x  = (const float*)d_in[0];
    const float* up = (const float*)d_in[1];
    const float* dn = (const float*)d_in[2];
    float* out      = (float*)d_out;

    const int rows    = in_sizes[0] / T_LEN;         // 2048
    const int threads = rows * TPR;                  // 4.19M
    flrelu_dot2p<<<threads / 256, 256, 0, stream>>>(x, up, dn, out);
}